// Round 1
// baseline (616.459 us; speedup 1.0000x reference)
//
#include <hip/hip_runtime.h>
#include <math.h>

#define NN 8192
#define HID 1024
#define PROJ 128

constexpr float INV_T = 1.0f / 0.07f;
constexpr float LN_EPS = 1e-12f;

// ---------------- Kernel 1: h = gelu(x @ W + b) ----------------
// 128x128 tile, BK=16, 8x8 micro-tile (split halves: tx*4 and 64+tx*4).
__global__ __launch_bounds__(256) void k_gemm1_gelu(
    const float* __restrict__ A, const float* __restrict__ W,
    const float* __restrict__ bias, float* __restrict__ Hout) {
  __shared__ float As[128 * 20];   // [i][k] stride 20 (pad keeps f4 align)
  __shared__ float Bs[16 * 128];   // [k][j]
  const int tid = threadIdx.x;
  const int bn = blockIdx.x * 128;
  const int bm = blockIdx.y * 128;
  const int tx = tid & 15, ty = tid >> 4;
  float acc[8][8];
#pragma unroll
  for (int m = 0; m < 8; ++m)
#pragma unroll
    for (int n = 0; n < 8; ++n) acc[m][n] = 0.f;

  for (int k0 = 0; k0 < HID; k0 += 16) {
#pragma unroll
    for (int l = 0; l < 2; ++l) {
      int idx = tid + l * 256;
      int i = idx >> 2, k4 = (idx & 3) * 4;
      *(float4*)&As[i * 20 + k4] =
          *(const float4*)(A + (size_t)(bm + i) * HID + k0 + k4);
    }
#pragma unroll
    for (int l = 0; l < 2; ++l) {
      int idx = tid + l * 256;
      int k = idx >> 5, j4 = (idx & 31) * 4;
      *(float4*)&Bs[k * 128 + j4] =
          *(const float4*)(W + (size_t)(k0 + k) * HID + bn + j4);
    }
    __syncthreads();
#pragma unroll
    for (int k = 0; k < 16; ++k) {
      float a[8];
#pragma unroll
      for (int h = 0; h < 2; ++h)
#pragma unroll
        for (int m = 0; m < 4; ++m)
          a[h * 4 + m] = As[(h * 64 + ty * 4 + m) * 20 + k];
      float4 b0 = *(const float4*)&Bs[k * 128 + tx * 4];
      float4 b1 = *(const float4*)&Bs[k * 128 + 64 + tx * 4];
      float b[8] = {b0.x, b0.y, b0.z, b0.w, b1.x, b1.y, b1.z, b1.w};
#pragma unroll
      for (int m = 0; m < 8; ++m)
#pragma unroll
        for (int n = 0; n < 8; ++n) acc[m][n] = fmaf(a[m], b[n], acc[m][n]);
    }
    __syncthreads();
  }
  float4 bv0 = *(const float4*)(bias + bn + tx * 4);
  float4 bv1 = *(const float4*)(bias + bn + 64 + tx * 4);
  const float bb[8] = {bv0.x, bv0.y, bv0.z, bv0.w, bv1.x, bv1.y, bv1.z, bv1.w};
  const float is2 = 0.70710678118654752f;
#pragma unroll
  for (int m = 0; m < 8; ++m) {
    int gi = bm + (m < 4 ? ty * 4 + m : 64 + ty * 4 + (m - 4));
    float o[8];
#pragma unroll
    for (int n = 0; n < 8; ++n) {
      float v = acc[m][n] + bb[n];
      o[n] = 0.5f * v * (1.0f + erff(v * is2));
    }
    *(float4*)(Hout + (size_t)gi * HID + bn + tx * 4) =
        make_float4(o[0], o[1], o[2], o[3]);
    *(float4*)(Hout + (size_t)gi * HID + bn + 64 + tx * 4) =
        make_float4(o[4], o[5], o[6], o[7]);
  }
}

// ---------------- Kernel 2: in-place LayerNorm per row ----------------
__global__ __launch_bounds__(256) void k_layernorm(
    float* __restrict__ Hm, const float* __restrict__ gamma,
    const float* __restrict__ beta) {
  const int row = blockIdx.x;
  const int tid = threadIdx.x;
  float* hr = Hm + (size_t)row * HID;
  float4 v = *(const float4*)(hr + tid * 4);
  float sum = v.x + v.y + v.z + v.w;
  float sq = v.x * v.x + v.y * v.y + v.z * v.z + v.w * v.w;
#pragma unroll
  for (int off = 32; off > 0; off >>= 1) {
    sum += __shfl_down(sum, off);
    sq += __shfl_down(sq, off);
  }
  __shared__ float rs[4], rq[4];
  __shared__ float mu_s, rstd_s;
  const int wave = tid >> 6, lane = tid & 63;
  if (lane == 0) { rs[wave] = sum; rq[wave] = sq; }
  __syncthreads();
  if (tid == 0) {
    float s = rs[0] + rs[1] + rs[2] + rs[3];
    float q = rq[0] + rq[1] + rq[2] + rq[3];
    float mu = s * (1.0f / HID);
    float var = q * (1.0f / HID) - mu * mu;
    mu_s = mu;
    rstd_s = rsqrtf(var + LN_EPS);
  }
  __syncthreads();
  const float mu = mu_s, r = rstd_s;
  float4 g = *(const float4*)(gamma + tid * 4);
  float4 b = *(const float4*)(beta + tid * 4);
  v.x = (v.x - mu) * r * g.x + b.x;
  v.y = (v.y - mu) * r * g.y + b.y;
  v.z = (v.z - mu) * r * g.z + b.z;
  v.w = (v.w - mu) * r * g.w + b.w;
  *(float4*)(hr + tid * 4) = v;
}

// ---------------- Kernel 3: zT[PROJ][NN] = (hn @ dec_w + dec_b)^T ----------
// 64 rows x 128 cols per block, BK=32, 4x8 micro-tile.
__global__ __launch_bounds__(256) void k_gemm2(
    const float* __restrict__ Hn, const float* __restrict__ Wd,
    const float* __restrict__ bd, float* __restrict__ zT) {
  __shared__ float As2[64 * 36];   // [i][k] stride 36
  __shared__ float Ws2[32 * 128];  // [k][j]
  const int tid = threadIdx.x;
  const int bm = blockIdx.x * 64;
  const int tx = tid & 15, ty = tid >> 4;
  float acc[4][8];
#pragma unroll
  for (int m = 0; m < 4; ++m)
#pragma unroll
    for (int n = 0; n < 8; ++n) acc[m][n] = 0.f;

  for (int k0 = 0; k0 < HID; k0 += 32) {
#pragma unroll
    for (int l = 0; l < 2; ++l) {
      int idx = tid + l * 256;
      int i = idx >> 3, k4 = (idx & 7) * 4;
      *(float4*)&As2[i * 36 + k4] =
          *(const float4*)(Hn + (size_t)(bm + i) * HID + k0 + k4);
    }
#pragma unroll
    for (int l = 0; l < 4; ++l) {
      int idx = tid + l * 256;
      int k = idx >> 5, j4 = (idx & 31) * 4;
      *(float4*)&Ws2[k * 128 + j4] =
          *(const float4*)(Wd + (size_t)(k0 + k) * PROJ + j4);
    }
    __syncthreads();
#pragma unroll
    for (int k = 0; k < 32; ++k) {
      float a[4];
#pragma unroll
      for (int m = 0; m < 4; ++m) a[m] = As2[(ty * 4 + m) * 36 + k];
      float4 b0 = *(const float4*)&Ws2[k * 128 + tx * 4];
      float4 b1 = *(const float4*)&Ws2[k * 128 + 64 + tx * 4];
      float b[8] = {b0.x, b0.y, b0.z, b0.w, b1.x, b1.y, b1.z, b1.w};
#pragma unroll
      for (int m = 0; m < 4; ++m)
#pragma unroll
        for (int n = 0; n < 8; ++n) acc[m][n] = fmaf(a[m], b[n], acc[m][n]);
    }
    __syncthreads();
  }
  float4 db0 = *(const float4*)(bd + tx * 4);
  float4 db1 = *(const float4*)(bd + 64 + tx * 4);
  const float bb[8] = {db0.x, db0.y, db0.z, db0.w, db1.x, db1.y, db1.z, db1.w};
#pragma unroll
  for (int n = 0; n < 8; ++n) {
    int gj = (n < 4 ? tx * 4 + n : 64 + tx * 4 + (n - 4));
    *(float4*)(zT + (size_t)gj * NN + bm + ty * 4) =
        make_float4(acc[0][n] + bb[n], acc[1][n] + bb[n],
                    acc[2][n] + bb[n], acc[3][n] + bb[n]);
  }
}

// ------- Kernel 4: online logsumexp partials over sims = Z Z^T / T --------
// grid (NN/64 i-chunks, 4 j-chunks). Block: 64 i-rows vs 2048 j in 16 tiles
// of 128 j, K=128 staged in 4 chunks of 32. Diagonal masked; positive dot
// written to pos_arr by the unique block/thread that computes it.
__global__ __launch_bounds__(256) void k_sim_partial(
    const float* __restrict__ zT, float* __restrict__ m_part,
    float* __restrict__ s_part, float* __restrict__ pos_arr) {
  __shared__ float zi_s[128 * 68];   // [k][i] stride 68
  __shared__ float zj_s[32 * 132];   // [k][j] stride 132
  const int tid = threadIdx.x;
  const int bi = blockIdx.x * 64;
  const int j0b = blockIdx.y * 2048;
  const int tx = tid & 15, ty = tid >> 4;

#pragma unroll
  for (int l = 0; l < 8; ++l) {
    int idx = tid + l * 256;
    int k = idx >> 4, i4 = (idx & 15) * 4;
    *(float4*)&zi_s[k * 68 + i4] =
        *(const float4*)(zT + (size_t)k * NN + bi + i4);
  }
  float mreg[4], sreg[4];
#pragma unroll
  for (int m = 0; m < 4; ++m) { mreg[m] = -1e30f; sreg[m] = 0.f; }

  for (int t = 0; t < 16; ++t) {
    const int j0 = j0b + t * 128;
    float acc[4][8];
#pragma unroll
    for (int m = 0; m < 4; ++m)
#pragma unroll
      for (int n = 0; n < 8; ++n) acc[m][n] = 0.f;
    for (int kc = 0; kc < 4; ++kc) {
      __syncthreads();   // also publishes zi_s before first use
#pragma unroll
      for (int l = 0; l < 4; ++l) {
        int idx = tid + l * 256;
        int k = idx >> 5, j4 = (idx & 31) * 4;
        *(float4*)&zj_s[k * 132 + j4] =
            *(const float4*)(zT + (size_t)(kc * 32 + k) * NN + j0 + j4);
      }
      __syncthreads();
#pragma unroll
      for (int k = 0; k < 32; ++k) {
        int kk = kc * 32 + k;
        float4 a4 = *(const float4*)&zi_s[kk * 68 + ty * 4];
        float4 b0 = *(const float4*)&zj_s[k * 132 + tx * 4];
        float4 b1 = *(const float4*)&zj_s[k * 132 + 64 + tx * 4];
        float a[4] = {a4.x, a4.y, a4.z, a4.w};
        float b[8] = {b0.x, b0.y, b0.z, b0.w, b1.x, b1.y, b1.z, b1.w};
#pragma unroll
        for (int m = 0; m < 4; ++m)
#pragma unroll
          for (int n = 0; n < 8; ++n) acc[m][n] = fmaf(a[m], b[n], acc[m][n]);
      }
    }
    // online (m, s) update for this 64x128 tile
#pragma unroll
    for (int m = 0; m < 4; ++m) {
      int gi = bi + ty * 4 + m;
      int partner = (gi + NN / 2) & (NN - 1);
#pragma unroll
      for (int n = 0; n < 8; ++n) {
        int gj = j0 + (n < 4 ? tx * 4 + n : 64 + tx * 4 + (n - 4));
        float d = acc[m][n];
        if (gj == partner) pos_arr[gi] = d;
        float v = (gj == gi) ? -1e30f : d * INV_T;
        float mn = fmaxf(mreg[m], v);
        sreg[m] = sreg[m] * __expf(mreg[m] - mn) + __expf(v - mn);
        mreg[m] = mn;
      }
    }
  }
  // combine the 16 tx-partials per row (alias zj_s as scratch)
  __syncthreads();
  float* mS = zj_s;              // [64][16]
  float* sS = zj_s + 64 * 16;    // [64][16]
#pragma unroll
  for (int m = 0; m < 4; ++m) {
    mS[(ty * 4 + m) * 16 + tx] = mreg[m];
    sS[(ty * 4 + m) * 16 + tx] = sreg[m];
  }
  __syncthreads();
  if (tid < 64) {
    float M = -1e30f;
    for (int g = 0; g < 16; ++g) M = fmaxf(M, mS[tid * 16 + g]);
    float S = 0.f;
    for (int g = 0; g < 16; ++g)
      S += sS[tid * 16 + g] * __expf(mS[tid * 16 + g] - M);
    m_part[(size_t)blockIdx.y * NN + bi + tid] = M;
    s_part[(size_t)blockIdx.y * NN + bi + tid] = S;
  }
}

// ---------------- Kernel 5: combine j-chunk partials per row --------------
__global__ __launch_bounds__(256) void k_combine(
    const float* __restrict__ m_part, const float* __restrict__ s_part,
    const float* __restrict__ pos_arr, float* __restrict__ row_loss) {
  const int i = blockIdx.x * 256 + threadIdx.x;
  float M = -1e30f;
#pragma unroll
  for (int jc = 0; jc < 4; ++jc) M = fmaxf(M, m_part[jc * NN + i]);
  float S = 0.f;
#pragma unroll
  for (int jc = 0; jc < 4; ++jc)
    S += s_part[jc * NN + i] * expf(m_part[jc * NN + i] - M);
  row_loss[i] = M + logf(S) - pos_arr[i] * INV_T;
}

// ---------------- Kernel 6: mean over rows ----------------
__global__ __launch_bounds__(256) void k_final(
    const float* __restrict__ row_loss, float* __restrict__ out) {
  const int tid = threadIdx.x;
  float s = 0.f;
#pragma unroll
  for (int l = 0; l < 32; ++l) s += row_loss[tid + l * 256];
#pragma unroll
  for (int off = 32; off > 0; off >>= 1) s += __shfl_down(s, off);
  __shared__ float red[4];
  const int wave = tid >> 6, lane = tid & 63;
  if (lane == 0) red[wave] = s;
  __syncthreads();
  if (tid == 0) out[0] = (red[0] + red[1] + red[2] + red[3]) * (1.0f / NN);
}

extern "C" void kernel_launch(void* const* d_in, const int* in_sizes, int n_in,
                              void* d_out, int out_size, void* d_ws,
                              size_t ws_size, hipStream_t stream) {
  const float* x       = (const float*)d_in[0];
  const float* dense_w = (const float*)d_in[1];
  const float* dense_b = (const float*)d_in[2];
  const float* ln_g    = (const float*)d_in[3];
  const float* ln_b    = (const float*)d_in[4];
  const float* dec_w   = (const float*)d_in[5];
  const float* dec_b   = (const float*)d_in[6];
  float* out = (float*)d_out;
  char* ws = (char*)d_ws;
  float* h        = (float*)(ws);                   // 8192*1024*4 = 32 MiB
  float* zT       = (float*)(ws + 33554432);        // 128*8192*4  =  4 MiB
  float* m_part   = (float*)(ws + 37748736);        // 4*8192*4
  float* s_part   = (float*)(ws + 37879808);        // 4*8192*4
  float* pos_arr  = (float*)(ws + 38010880);        // 8192*4
  float* row_loss = (float*)(ws + 38043648);        // 8192*4

  k_gemm1_gelu<<<dim3(8, 64), 256, 0, stream>>>(x, dense_w, dense_b, h);
  k_layernorm<<<dim3(NN), 256, 0, stream>>>(h, ln_g, ln_b);
  k_gemm2<<<dim3(NN / 64), 256, 0, stream>>>(h, dec_w, dec_b, zT);
  k_sim_partial<<<dim3(NN / 64, 4), 256, 0, stream>>>(zT, m_part, s_part,
                                                      pos_arr);
  k_combine<<<dim3(NN / 256), 256, 0, stream>>>(m_part, s_part, pos_arr,
                                                row_loss);
  k_final<<<dim3(1), 256, 0, stream>>>(row_loss, out);
}

// Round 2
// 204.873 us; speedup vs baseline: 3.0090x; 3.0090x over previous
//
#include <hip/hip_runtime.h>
#include <math.h>
#include <stdint.h>

#define NN 8192
#define HID 1024
#define PROJ 128

constexpr float INV_T = 1.0f / 0.07f;
constexpr float LN_EPS = 1e-12f;
// exp(x) = exp2(x * log2e); logits are d * INV_T  ->  exp2(d * CC - M * CC)
constexpr float CC = 14.285714285714286f * 1.4426950408889634f;

typedef __bf16 bf16x8 __attribute__((ext_vector_type(8)));
typedef float f32x4 __attribute__((ext_vector_type(4)));

#define EXP2(x) __builtin_amdgcn_exp2f(x)

#define GLD16(g, l)                                                     \
  __builtin_amdgcn_global_load_lds(                                     \
      (const __attribute__((address_space(1))) uint32_t*)(g),           \
      (__attribute__((address_space(3))) uint32_t*)(l), 16, 0, 0)

__device__ __forceinline__ uint16_t f2bf(float f) {
  union { float f; uint32_t u; } c; c.f = f;
  uint32_t r = (c.u + 0x7FFFu + ((c.u >> 16) & 1u)) >> 16;
  return (uint16_t)r;
}
__device__ __forceinline__ float bf2f(uint16_t u) {
  union { uint32_t u; float f; } c; c.u = ((uint32_t)u) << 16;
  return c.f;
}

// ---------------- convert fp32 -> bf16, same layout ----------------
__global__ __launch_bounds__(256) void k_conv(const float* __restrict__ in,
                                              uint16_t* __restrict__ out) {
  int i = (blockIdx.x * 256 + threadIdx.x) * 4;
  float4 v = *(const float4*)(in + i);
  ushort4 o;
  o.x = f2bf(v.x); o.y = f2bf(v.y); o.z = f2bf(v.z); o.w = f2bf(v.w);
  *(ushort4*)(out + i) = o;
}

// ------------- transpose+convert: in fp32 [R][C] -> out bf16 [C][R] -------
__global__ __launch_bounds__(256) void k_transpose(const float* __restrict__ in,
                                                   uint16_t* __restrict__ out,
                                                   int R, int C) {
  __shared__ uint16_t t[32][33];
  const int cb = blockIdx.x * 32, rb = blockIdx.y * 32;
  const int tr = threadIdx.x >> 3, tc4 = (threadIdx.x & 7) * 4;
  float4 v = *(const float4*)(in + (size_t)(rb + tr) * C + cb + tc4);
  t[tc4 + 0][tr] = f2bf(v.x);
  t[tc4 + 1][tr] = f2bf(v.y);
  t[tc4 + 2][tr] = f2bf(v.z);
  t[tc4 + 3][tr] = f2bf(v.w);
  __syncthreads();
  const int oc = threadIdx.x >> 3, or4 = (threadIdx.x & 7) * 4;
  ushort4 o;
  o.x = t[oc][or4 + 0]; o.y = t[oc][or4 + 1];
  o.z = t[oc][or4 + 2]; o.w = t[oc][or4 + 3];
  *(ushort4*)(out + (size_t)(cb + oc) * R + rb + or4) = o;
}

// ---------------- GEMM1: h = gelu(x @ W + b), bf16 MFMA ----------------
// 128x128 tile, BK=32, global_load_lds staging (m97 recipe).
__global__ __launch_bounds__(256) void k_gemm1(
    const uint16_t* __restrict__ Ab, const uint16_t* __restrict__ Bt,
    const float* __restrict__ bias, uint16_t* __restrict__ Hout) {
  __shared__ __align__(16) uint16_t As[128 * 32];
  __shared__ __align__(16) uint16_t Bs[128 * 32];
  const int tid = threadIdx.x;
  const int bn = blockIdx.x * 128, bm = blockIdx.y * 128;
  const int wave = tid >> 6, lane = tid & 63;
  const int wx = wave & 1, wy = wave >> 1;
  const int col = lane & 15, quad = lane >> 4;
  f32x4 acc[4][4] = {};
  const char* Abase = (const char*)Ab;
  const char* Bbase = (const char*)Bt;
  for (int k0 = 0; k0 < HID; k0 += 32) {
    __syncthreads();
#pragma unroll
    for (int l = 0; l < 2; ++l) {
      int off = tid * 16 + l * 4096;
      int row = off >> 6, inner = off & 63;
      GLD16(Abase + ((size_t)(bm + row) * HID + k0) * 2 + inner,
            (char*)As + off);
    }
#pragma unroll
    for (int l = 0; l < 2; ++l) {
      int off = tid * 16 + l * 4096;
      int row = off >> 6, inner = off & 63;
      GLD16(Bbase + ((size_t)(bn + row) * HID + k0) * 2 + inner,
            (char*)Bs + off);
    }
    __syncthreads();
    bf16x8 a[4], b[4];
#pragma unroll
    for (int mt = 0; mt < 4; ++mt)
      a[mt] = *(const bf16x8*)&As[(wy * 64 + mt * 16 + col) * 32 + quad * 8];
#pragma unroll
    for (int nt = 0; nt < 4; ++nt)
      b[nt] = *(const bf16x8*)&Bs[(wx * 64 + nt * 16 + col) * 32 + quad * 8];
#pragma unroll
    for (int mt = 0; mt < 4; ++mt)
#pragma unroll
      for (int nt = 0; nt < 4; ++nt)
        acc[mt][nt] = __builtin_amdgcn_mfma_f32_16x16x32_bf16(
            a[mt], b[nt], acc[mt][nt], 0, 0, 0);
  }
  const float is2 = 0.70710678118654752f;
#pragma unroll
  for (int nt = 0; nt < 4; ++nt) {
    int gj = bn + wx * 64 + nt * 16 + col;
    float bv = bias[gj];
#pragma unroll
    for (int mt = 0; mt < 4; ++mt) {
#pragma unroll
      for (int r = 0; r < 4; ++r) {
        int gi = bm + wy * 64 + mt * 16 + quad * 4 + r;
        float v = acc[mt][nt][r] + bv;
        float g = 0.5f * v * (1.0f + erff(v * is2));
        Hout[(size_t)gi * HID + gj] = f2bf(g);
      }
    }
  }
}

// ---------------- LayerNorm in-place on bf16 h ----------------
__global__ __launch_bounds__(256) void k_layernorm(
    uint16_t* __restrict__ Hm, const float* __restrict__ gamma,
    const float* __restrict__ beta) {
  const int row = blockIdx.x;
  const int tid = threadIdx.x;
  uint16_t* hr = Hm + (size_t)row * HID;
  ushort4 u = *(const ushort4*)(hr + tid * 4);
  float f0 = bf2f(u.x), f1 = bf2f(u.y), f2 = bf2f(u.z), f3 = bf2f(u.w);
  float sum = f0 + f1 + f2 + f3;
  float sq = f0 * f0 + f1 * f1 + f2 * f2 + f3 * f3;
#pragma unroll
  for (int off = 32; off > 0; off >>= 1) {
    sum += __shfl_down(sum, off);
    sq += __shfl_down(sq, off);
  }
  __shared__ float rs[4], rq[4];
  __shared__ float mu_s, rstd_s;
  const int wave = tid >> 6, lane = tid & 63;
  if (lane == 0) { rs[wave] = sum; rq[wave] = sq; }
  __syncthreads();
  if (tid == 0) {
    float s = rs[0] + rs[1] + rs[2] + rs[3];
    float q = rq[0] + rq[1] + rq[2] + rq[3];
    float mu = s * (1.0f / HID);
    float var = q * (1.0f / HID) - mu * mu;
    mu_s = mu;
    rstd_s = rsqrtf(var + LN_EPS);
  }
  __syncthreads();
  const float mu = mu_s, r = rstd_s;
  float4 g = *(const float4*)(gamma + tid * 4);
  float4 b = *(const float4*)(beta + tid * 4);
  ushort4 o;
  o.x = f2bf((f0 - mu) * r * g.x + b.x);
  o.y = f2bf((f1 - mu) * r * g.y + b.y);
  o.z = f2bf((f2 - mu) * r * g.z + b.z);
  o.w = f2bf((f3 - mu) * r * g.w + b.w);
  *(ushort4*)(hr + tid * 4) = o;
}

// ------------- GEMM2: z = hn @ dec_w + b, bf16 MFMA, 64x128 tile ----------
__global__ __launch_bounds__(256) void k_gemm2(
    const uint16_t* __restrict__ Hn, const uint16_t* __restrict__ Wt2,
    const float* __restrict__ bd, uint16_t* __restrict__ Z) {
  __shared__ __align__(16) uint16_t As2[64 * 32];
  __shared__ __align__(16) uint16_t Bs2[128 * 32];
  const int tid = threadIdx.x;
  const int bm = blockIdx.x * 64;
  const int wave = tid >> 6, lane = tid & 63;
  const int wx = wave & 1, wy = wave >> 1;
  const int col = lane & 15, quad = lane >> 4;
  f32x4 acc[2][4] = {};
  const char* Abase = (const char*)Hn;
  const char* Bbase = (const char*)Wt2;
  for (int k0 = 0; k0 < HID; k0 += 32) {
    __syncthreads();
    {
      int off = tid * 16;
      int row = off >> 6, inner = off & 63;
      GLD16(Abase + ((size_t)(bm + row) * HID + k0) * 2 + inner,
            (char*)As2 + off);
    }
#pragma unroll
    for (int l = 0; l < 2; ++l) {
      int off = tid * 16 + l * 4096;
      int row = off >> 6, inner = off & 63;
      GLD16(Bbase + ((size_t)row * HID + k0) * 2 + inner, (char*)Bs2 + off);
    }
    __syncthreads();
    bf16x8 a[2], b[4];
#pragma unroll
    for (int mt = 0; mt < 2; ++mt)
      a[mt] = *(const bf16x8*)&As2[(wy * 32 + mt * 16 + col) * 32 + quad * 8];
#pragma unroll
    for (int nt = 0; nt < 4; ++nt)
      b[nt] = *(const bf16x8*)&Bs2[(wx * 64 + nt * 16 + col) * 32 + quad * 8];
#pragma unroll
    for (int mt = 0; mt < 2; ++mt)
#pragma unroll
      for (int nt = 0; nt < 4; ++nt)
        acc[mt][nt] = __builtin_amdgcn_mfma_f32_16x16x32_bf16(
            a[mt], b[nt], acc[mt][nt], 0, 0, 0);
  }
#pragma unroll
  for (int nt = 0; nt < 4; ++nt) {
    int gj = wx * 64 + nt * 16 + col;
    float bv = bd[gj];
#pragma unroll
    for (int mt = 0; mt < 2; ++mt)
#pragma unroll
      for (int r = 0; r < 4; ++r) {
        int gi = bm + wy * 32 + mt * 16 + quad * 4 + r;
        Z[(size_t)gi * PROJ + gj] = f2bf(acc[mt][nt][r] + bv);
      }
  }
}

// ---------------- flash-style online logsumexp over Z Z^T ----------------
__device__ __forceinline__ void lse_update(float& m, float& s, float v0,
                                           float v1, float v2, float v3) {
  float lm = fmaxf(fmaxf(v0, v1), fmaxf(v2, v3));
  float mn = fmaxf(m, lm);
  float t = mn * CC;
  s = s * EXP2(m * CC - t) + EXP2(v0 * CC - t) + EXP2(v1 * CC - t) +
      EXP2(v2 * CC - t) + EXP2(v3 * CC - t);
  m = mn;
}

__global__ __launch_bounds__(256) void k_sim(const uint16_t* __restrict__ Z,
                                             float* __restrict__ m_part,
                                             float* __restrict__ s_part,
                                             float* __restrict__ pos_arr) {
  __shared__ __align__(16) uint16_t Zi[128 * 136];
  __shared__ __align__(16) uint16_t Zj[128 * 136];
  const int tid = threadIdx.x;
  const int bi = blockIdx.x * 128;
  const int chunk = blockIdx.y;
  const int wave = tid >> 6, lane = tid & 63;
  const int wx = wave & 1, wy = wave >> 1;
  const int col = lane & 15, quad = lane >> 4;

#pragma unroll
  for (int l = 0; l < 8; ++l) {
    int idx = tid + l * 256;
    int row = idx >> 4, kq = (idx & 15) * 8;
    *(uint4*)&Zi[row * 136 + kq] = *(const uint4*)(Z + (size_t)(bi + row) * PROJ + kq);
  }
  float mrow[16], srow[16];
#pragma unroll
  for (int i = 0; i < 16; ++i) { mrow[i] = -INFINITY; srow[i] = 0.f; }

  const int jbase = chunk * 1024;
  for (int t = 0; t < 8; ++t) {
    const int j0 = jbase + t * 128;
    __syncthreads();
#pragma unroll
    for (int l = 0; l < 8; ++l) {
      int idx = tid + l * 256;
      int row = idx >> 4, kq = (idx & 15) * 8;
      *(uint4*)&Zj[row * 136 + kq] =
          *(const uint4*)(Z + (size_t)(j0 + row) * PROJ + kq);
    }
    __syncthreads();
    f32x4 acc[4][4] = {};
#pragma unroll
    for (int kc = 0; kc < 4; ++kc) {
      bf16x8 a[4], b[4];
#pragma unroll
      for (int mt = 0; mt < 4; ++mt)
        a[mt] = *(const bf16x8*)&Zi[(wy * 64 + mt * 16 + col) * 136 +
                                    kc * 32 + quad * 8];
#pragma unroll
      for (int nt = 0; nt < 4; ++nt)
        b[nt] = *(const bf16x8*)&Zj[(wx * 64 + nt * 16 + col) * 136 +
                                    kc * 32 + quad * 8];
#pragma unroll
      for (int mt = 0; mt < 4; ++mt)
#pragma unroll
        for (int nt = 0; nt < 4; ++nt)
          acc[mt][nt] = __builtin_amdgcn_mfma_f32_16x16x32_bf16(
              a[mt], b[nt], acc[mt][nt], 0, 0, 0);
    }
    const bool is_diag = (j0 == bi);
    const bool is_pos = (j0 == ((bi + NN / 2) & (NN - 1)));
    if (!(is_diag || is_pos)) {
#pragma unroll
      for (int mt = 0; mt < 4; ++mt)
#pragma unroll
        for (int r = 0; r < 4; ++r)
          lse_update(mrow[mt * 4 + r], srow[mt * 4 + r], acc[mt][0][r],
                     acc[mt][1][r], acc[mt][2][r], acc[mt][3][r]);
    } else {
#pragma unroll
      for (int mt = 0; mt < 4; ++mt)
#pragma unroll
        for (int r = 0; r < 4; ++r) {
          int gi = bi + wy * 64 + mt * 16 + quad * 4 + r;
          int partner = (gi + NN / 2) & (NN - 1);
          float v[4];
#pragma unroll
          for (int nt = 0; nt < 4; ++nt) {
            int gj = j0 + wx * 64 + nt * 16 + col;
            float d = acc[mt][nt][r];
            if (is_pos && gj == partner) pos_arr[gi] = d;
            v[nt] = (is_diag && gj == gi) ? -INFINITY : d;
          }
          lse_update(mrow[mt * 4 + r], srow[mt * 4 + r], v[0], v[1], v[2],
                     v[3]);
        }
    }
  }
  // reduce (m,s) across the 16 lanes sharing the same rows
#pragma unroll
  for (int ri = 0; ri < 16; ++ri) {
#pragma unroll
    for (int off = 1; off < 16; off <<= 1) {
      float om = __shfl_xor(mrow[ri], off, 64);
      float os = __shfl_xor(srow[ri], off, 64);
      float mn = fmaxf(mrow[ri], om);
      float t = mn * CC;
      srow[ri] = srow[ri] * EXP2(mrow[ri] * CC - t) + os * EXP2(om * CC - t);
      mrow[ri] = mn;
    }
  }
  if (col == 0) {
    int p = chunk * 2 + wx;
#pragma unroll
    for (int ri = 0; ri < 16; ++ri) {
      int gi = bi + wy * 64 + (ri >> 2) * 16 + quad * 4 + (ri & 3);
      m_part[(size_t)p * NN + gi] = mrow[ri];
      s_part[(size_t)p * NN + gi] = srow[ri];
    }
  }
}

// ---------------- combine partials per row ----------------
__global__ __launch_bounds__(256) void k_combine(
    const float* __restrict__ m_part, const float* __restrict__ s_part,
    const float* __restrict__ pos_arr, float* __restrict__ row_loss) {
  const int i = blockIdx.x * 256 + threadIdx.x;
  float M = -INFINITY;
#pragma unroll
  for (int p = 0; p < 16; ++p) M = fmaxf(M, m_part[(size_t)p * NN + i]);
  float S = 0.f;
  float t = M * CC;
#pragma unroll
  for (int p = 0; p < 16; ++p)
    S += s_part[(size_t)p * NN + i] * EXP2(m_part[(size_t)p * NN + i] * CC - t);
  row_loss[i] = (M - pos_arr[i]) * INV_T + logf(S);
}

// ---------------- mean over rows ----------------
__global__ __launch_bounds__(256) void k_final(
    const float* __restrict__ row_loss, float* __restrict__ out) {
  const int tid = threadIdx.x;
  float s = 0.f;
#pragma unroll
  for (int l = 0; l < 32; ++l) s += row_loss[tid + l * 256];
#pragma unroll
  for (int off = 32; off > 0; off >>= 1) s += __shfl_down(s, off);
  __shared__ float red[4];
  const int wave = tid >> 6, lane = tid & 63;
  if (lane == 0) red[wave] = s;
  __syncthreads();
  if (tid == 0) out[0] = (red[0] + red[1] + red[2] + red[3]) * (1.0f / NN);
}

extern "C" void kernel_launch(void* const* d_in, const int* in_sizes, int n_in,
                              void* d_out, int out_size, void* d_ws,
                              size_t ws_size, hipStream_t stream) {
  const float* x       = (const float*)d_in[0];
  const float* dense_w = (const float*)d_in[1];
  const float* dense_b = (const float*)d_in[2];
  const float* ln_g    = (const float*)d_in[3];
  const float* ln_b    = (const float*)d_in[4];
  const float* dec_w   = (const float*)d_in[5];
  const float* dec_b   = (const float*)d_in[6];
  float* out = (float*)d_out;
  char* ws = (char*)d_ws;
  // Phase 1 layout
  uint16_t* xb = (uint16_t*)(ws);              // 16 MiB [8192][1024] bf16
  uint16_t* wt = (uint16_t*)(ws + 16777216);   //  2 MiB [1024][1024] bf16 (W^T)
  uint16_t* h  = (uint16_t*)(ws + 18874368);   // 16 MiB [8192][1024] bf16
  // Phase 2 layout (reuses xb region after GEMM1 consumed it)
  uint16_t* wt2     = (uint16_t*)(ws);             // 256 KiB [128][1024]
  uint16_t* z       = (uint16_t*)(ws + 262144);    //   2 MiB [8192][128]
  float*    m_part  = (float*)(ws + 2359296);      // 512 KiB [16][8192]
  float*    s_part  = (float*)(ws + 2883584);      // 512 KiB
  float*    pos_arr = (float*)(ws + 3407872);      //  32 KiB
  float*    row_loss= (float*)(ws + 3440640);      //  32 KiB

  k_conv<<<dim3(NN * HID / 1024), 256, 0, stream>>>(x, xb);
  k_transpose<<<dim3(32, 32), 256, 0, stream>>>(dense_w, wt, HID, HID);
  k_gemm1<<<dim3(HID / 128, NN / 128), 256, 0, stream>>>(xb, wt, dense_b, h);
  // xb dead from here; phase-2 buffers live in its region
  k_transpose<<<dim3(PROJ / 32, HID / 32), 256, 0, stream>>>(dec_w, wt2, HID,
                                                             PROJ);
  k_layernorm<<<dim3(NN), 256, 0, stream>>>(h, ln_g, ln_b);
  k_gemm2<<<dim3(NN / 64), 256, 0, stream>>>(h, wt2, dec_b, z);
  k_sim<<<dim3(NN / 128, 8), 256, 0, stream>>>(z, m_part, s_part, pos_arr);
  k_combine<<<dim3(NN / 256), 256, 0, stream>>>(m_part, s_part, pos_arr,
                                                row_loss);
  k_final<<<dim3(1), 256, 0, stream>>>(row_loss, out);
}

// Round 3
// 199.688 us; speedup vs baseline: 3.0871x; 1.0260x over previous
//
#include <hip/hip_runtime.h>
#include <math.h>
#include <stdint.h>

#define NN 8192
#define HID 1024
#define PROJ 128

constexpr float INV_T = 1.0f / 0.07f;
constexpr float LN_EPS = 1e-12f;
// exp(x) = exp2(x * log2e); logits are d * INV_T -> exp2((d - M) * CC)
constexpr float CC = 14.285714285714286f * 1.4426950408889634f;

typedef __bf16 bf16x8 __attribute__((ext_vector_type(8)));
typedef float f32x4 __attribute__((ext_vector_type(4)));

#define EXP2(x) __builtin_amdgcn_exp2f(x)

#define GLD16(g, l)                                                     \
  __builtin_amdgcn_global_load_lds(                                     \
      (const __attribute__((address_space(1))) uint32_t*)(g),           \
      (__attribute__((address_space(3))) uint32_t*)(l), 16, 0, 0)

__device__ __forceinline__ uint16_t f2bf(float f) {
  union { float f; uint32_t u; } c; c.f = f;
  uint32_t r = (c.u + 0x7FFFu + ((c.u >> 16) & 1u)) >> 16;
  return (uint16_t)r;
}
__device__ __forceinline__ float bf2f(uint16_t u) {
  union { uint32_t u; float f; } c; c.u = ((uint32_t)u) << 16;
  return c.f;
}

// gelu(v) ~= v * sigmoid(2u), u = 0.79788456(v + 0.044715 v^3)
// max |err| vs erf-gelu ~3e-3, below bf16 noise. NaN-free for all v.
__device__ __forceinline__ float gelu_f(float v) {
  float w = v * v;
  float u = v * fmaf(w, 0.0356774081f, 0.7978845608f);
  float e = EXP2(u * -2.8853900818f);  // e^{-2u}
  return v * __builtin_amdgcn_rcpf(1.0f + e);
}

// ---------------- convert fp32 -> bf16, same layout ----------------
__global__ __launch_bounds__(256) void k_conv(const float* __restrict__ in,
                                              uint16_t* __restrict__ out) {
  int i = (blockIdx.x * 256 + threadIdx.x) * 4;
  float4 v = *(const float4*)(in + i);
  ushort4 o;
  o.x = f2bf(v.x); o.y = f2bf(v.y); o.z = f2bf(v.z); o.w = f2bf(v.w);
  *(ushort4*)(out + i) = o;
}

// ------------- transpose+convert: in fp32 [R][C] -> out bf16 [C][R] -------
__global__ __launch_bounds__(256) void k_transpose(const float* __restrict__ in,
                                                   uint16_t* __restrict__ out,
                                                   int R, int C) {
  __shared__ uint16_t t[32][33];
  const int cb = blockIdx.x * 32, rb = blockIdx.y * 32;
  const int tr = threadIdx.x >> 3, tc4 = (threadIdx.x & 7) * 4;
  float4 v = *(const float4*)(in + (size_t)(rb + tr) * C + cb + tc4);
  t[tc4 + 0][tr] = f2bf(v.x);
  t[tc4 + 1][tr] = f2bf(v.y);
  t[tc4 + 2][tr] = f2bf(v.z);
  t[tc4 + 3][tr] = f2bf(v.w);
  __syncthreads();
  const int oc = threadIdx.x >> 3, or4 = (threadIdx.x & 7) * 4;
  ushort4 o;
  o.x = t[oc][or4 + 0]; o.y = t[oc][or4 + 1];
  o.z = t[oc][or4 + 2]; o.w = t[oc][or4 + 3];
  *(ushort4*)(out + (size_t)(cb + oc) * R + rb + or4) = o;
}

// ---------------- GEMM1: h = gelu(x @ W + b), bf16 MFMA ----------------
// 64x128 tile, BK=32, grid (8,128)=1024 blocks -> 4 blocks/CU resident.
__global__ __launch_bounds__(256) void k_gemm1(
    const uint16_t* __restrict__ Ab, const uint16_t* __restrict__ Bt,
    const float* __restrict__ bias, uint16_t* __restrict__ Hout) {
  __shared__ __align__(16) uint16_t As[64 * 32];
  __shared__ __align__(16) uint16_t Bs[128 * 32];
  const int tid = threadIdx.x;
  const int bn = blockIdx.x * 128, bm = blockIdx.y * 64;
  const int wave = tid >> 6, lane = tid & 63;
  const int wx = wave & 1, wy = wave >> 1;
  const int col = lane & 15, quad = lane >> 4;
  f32x4 acc[2][4] = {};
  const char* Abase = (const char*)Ab;
  const char* Bbase = (const char*)Bt;
  for (int k0 = 0; k0 < HID; k0 += 32) {
    __syncthreads();
    {
      int off = tid * 16;
      int row = off >> 6, inner = off & 63;
      GLD16(Abase + ((size_t)(bm + row) * HID + k0) * 2 + inner,
            (char*)As + off);
    }
#pragma unroll
    for (int l = 0; l < 2; ++l) {
      int off = tid * 16 + l * 4096;
      int row = off >> 6, inner = off & 63;
      GLD16(Bbase + ((size_t)(bn + row) * HID + k0) * 2 + inner,
            (char*)Bs + off);
    }
    __syncthreads();
    bf16x8 a[2], b[4];
#pragma unroll
    for (int mt = 0; mt < 2; ++mt)
      a[mt] = *(const bf16x8*)&As[(wy * 32 + mt * 16 + col) * 32 + quad * 8];
#pragma unroll
    for (int nt = 0; nt < 4; ++nt)
      b[nt] = *(const bf16x8*)&Bs[(wx * 64 + nt * 16 + col) * 32 + quad * 8];
#pragma unroll
    for (int mt = 0; mt < 2; ++mt)
#pragma unroll
      for (int nt = 0; nt < 4; ++nt)
        acc[mt][nt] = __builtin_amdgcn_mfma_f32_16x16x32_bf16(
            a[mt], b[nt], acc[mt][nt], 0, 0, 0);
  }
#pragma unroll
  for (int nt = 0; nt < 4; ++nt) {
    int gj = bn + wx * 64 + nt * 16 + col;
    float bv = bias[gj];
#pragma unroll
    for (int mt = 0; mt < 2; ++mt)
#pragma unroll
      for (int r = 0; r < 4; ++r) {
        int gi = bm + wy * 32 + mt * 16 + quad * 4 + r;
        Hout[(size_t)gi * HID + gj] = f2bf(gelu_f(acc[mt][nt][r] + bv));
      }
  }
}

// ---------------- LayerNorm in-place on bf16 h ----------------
__global__ __launch_bounds__(256) void k_layernorm(
    uint16_t* __restrict__ Hm, const float* __restrict__ gamma,
    const float* __restrict__ beta) {
  const int row = blockIdx.x;
  const int tid = threadIdx.x;
  uint16_t* hr = Hm + (size_t)row * HID;
  ushort4 u = *(const ushort4*)(hr + tid * 4);
  float f0 = bf2f(u.x), f1 = bf2f(u.y), f2 = bf2f(u.z), f3 = bf2f(u.w);
  float sum = f0 + f1 + f2 + f3;
  float sq = f0 * f0 + f1 * f1 + f2 * f2 + f3 * f3;
#pragma unroll
  for (int off = 32; off > 0; off >>= 1) {
    sum += __shfl_down(sum, off);
    sq += __shfl_down(sq, off);
  }
  __shared__ float rs[4], rq[4];
  __shared__ float mu_s, rstd_s;
  const int wave = tid >> 6, lane = tid & 63;
  if (lane == 0) { rs[wave] = sum; rq[wave] = sq; }
  __syncthreads();
  if (tid == 0) {
    float s = rs[0] + rs[1] + rs[2] + rs[3];
    float q = rq[0] + rq[1] + rq[2] + rq[3];
    float mu = s * (1.0f / HID);
    float var = q * (1.0f / HID) - mu * mu;
    mu_s = mu;
    rstd_s = rsqrtf(var + LN_EPS);
  }
  __syncthreads();
  const float mu = mu_s, r = rstd_s;
  float4 g = *(const float4*)(gamma + tid * 4);
  float4 b = *(const float4*)(beta + tid * 4);
  ushort4 o;
  o.x = f2bf((f0 - mu) * r * g.x + b.x);
  o.y = f2bf((f1 - mu) * r * g.y + b.y);
  o.z = f2bf((f2 - mu) * r * g.z + b.z);
  o.w = f2bf((f3 - mu) * r * g.w + b.w);
  *(ushort4*)(hr + tid * 4) = o;
}

// ------------- GEMM2: z = hn @ dec_w + b, 32x128 tile, grid 256 -----------
__global__ __launch_bounds__(256) void k_gemm2(
    const uint16_t* __restrict__ Hn, const uint16_t* __restrict__ Wt2,
    const float* __restrict__ bd, uint16_t* __restrict__ Z) {
  __shared__ __align__(16) uint16_t As2[32 * 32];
  __shared__ __align__(16) uint16_t Bs2[128 * 32];
  const int tid = threadIdx.x;
  const int bm = blockIdx.x * 32;
  const int wave = tid >> 6, lane = tid & 63;
  const int wx = wave & 1, wy = wave >> 1;
  const int col = lane & 15, quad = lane >> 4;
  f32x4 acc[4] = {};
  const char* Abase = (const char*)Hn;
  const char* Bbase = (const char*)Wt2;
  for (int k0 = 0; k0 < HID; k0 += 32) {
    __syncthreads();
    if (tid < 128) {
      int off = tid * 16;
      int row = off >> 6, inner = off & 63;
      GLD16(Abase + ((size_t)(bm + row) * HID + k0) * 2 + inner,
            (char*)As2 + off);
    }
#pragma unroll
    for (int l = 0; l < 2; ++l) {
      int off = tid * 16 + l * 4096;
      int row = off >> 6, inner = off & 63;
      GLD16(Bbase + ((size_t)row * HID + k0) * 2 + inner, (char*)Bs2 + off);
    }
    __syncthreads();
    bf16x8 a = *(const bf16x8*)&As2[(wy * 16 + col) * 32 + quad * 8];
#pragma unroll
    for (int nt = 0; nt < 4; ++nt) {
      bf16x8 b = *(const bf16x8*)&Bs2[(wx * 64 + nt * 16 + col) * 32 + quad * 8];
      acc[nt] = __builtin_amdgcn_mfma_f32_16x16x32_bf16(a, b, acc[nt], 0, 0, 0);
    }
  }
#pragma unroll
  for (int nt = 0; nt < 4; ++nt) {
    int gj = wx * 64 + nt * 16 + col;
    float bv = bd[gj];
#pragma unroll
    for (int r = 0; r < 4; ++r) {
      int gi = bm + wy * 16 + quad * 4 + r;
      Z[(size_t)gi * PROJ + gj] = f2bf(acc[nt][r] + bv);
    }
  }
}

// ---------------- flash-style online logsumexp over Z Z^T ----------------
// 64i x 128j tiles; Zi fragments in registers, Zj in LDS.
// grid (128, 16): each block does 4 j-tiles (512 cols).
__device__ __forceinline__ void lse_update(float& m, float& s, float v0,
                                           float v1, float v2, float v3) {
  float lm = fmaxf(fmaxf(v0, v1), fmaxf(v2, v3));
  float mn = fmaxf(m, lm);
  float t = mn * CC;
  s = s * EXP2(m * CC - t) + EXP2(v0 * CC - t) + EXP2(v1 * CC - t) +
      EXP2(v2 * CC - t) + EXP2(v3 * CC - t);
  m = mn;
}

__global__ __launch_bounds__(256) void k_sim(const uint16_t* __restrict__ Z,
                                             float* __restrict__ m_part,
                                             float* __restrict__ s_part,
                                             float* __restrict__ pos_arr) {
  __shared__ __align__(16) uint16_t Zj[128 * 136];
  const int tid = threadIdx.x;
  const int bi = blockIdx.x * 64;
  const int chunk = blockIdx.y;
  const int wave = tid >> 6, lane = tid & 63;
  const int wx = wave & 1, wy = wave >> 1;
  const int col = lane & 15, quad = lane >> 4;

  // A fragments from global, once (L2/L3-hot; Z is 2 MiB)
  bf16x8 afr[2][4];
#pragma unroll
  for (int mt = 0; mt < 2; ++mt)
#pragma unroll
    for (int kc = 0; kc < 4; ++kc)
      afr[mt][kc] = *(const bf16x8*)(Z +
          (size_t)(bi + wy * 32 + mt * 16 + col) * PROJ + kc * 32 + quad * 8);

  float mrow[8], srow[8];
#pragma unroll
  for (int i = 0; i < 8; ++i) { mrow[i] = -INFINITY; srow[i] = 0.f; }

  const int jbase = chunk * 512;
  for (int t = 0; t < 4; ++t) {
    const int j0 = jbase + t * 128;
    __syncthreads();
#pragma unroll
    for (int l = 0; l < 8; ++l) {
      int idx = tid + l * 256;
      int row = idx >> 4, kq = (idx & 15) * 8;
      *(uint4*)&Zj[row * 136 + kq] =
          *(const uint4*)(Z + (size_t)(j0 + row) * PROJ + kq);
    }
    __syncthreads();
    f32x4 acc[2][4] = {};
#pragma unroll
    for (int kc = 0; kc < 4; ++kc) {
      bf16x8 b[4];
#pragma unroll
      for (int nt = 0; nt < 4; ++nt)
        b[nt] = *(const bf16x8*)&Zj[(wx * 64 + nt * 16 + col) * 136 +
                                    kc * 32 + quad * 8];
#pragma unroll
      for (int mt = 0; mt < 2; ++mt)
#pragma unroll
        for (int nt = 0; nt < 4; ++nt)
          acc[mt][nt] = __builtin_amdgcn_mfma_f32_16x16x32_bf16(
              afr[mt][kc], b[nt], acc[mt][nt], 0, 0, 0);
    }
    const bool is_diag = (j0 == (bi & ~127));
    const bool is_pos = (j0 == (((bi + NN / 2) & (NN - 1)) & ~127));
    if (!(is_diag || is_pos)) {
#pragma unroll
      for (int mt = 0; mt < 2; ++mt)
#pragma unroll
        for (int r = 0; r < 4; ++r)
          lse_update(mrow[mt * 4 + r], srow[mt * 4 + r], acc[mt][0][r],
                     acc[mt][1][r], acc[mt][2][r], acc[mt][3][r]);
    } else {
#pragma unroll
      for (int mt = 0; mt < 2; ++mt)
#pragma unroll
        for (int r = 0; r < 4; ++r) {
          int gi = bi + wy * 32 + mt * 16 + quad * 4 + r;
          int partner = (gi + NN / 2) & (NN - 1);
          float v[4];
#pragma unroll
          for (int nt = 0; nt < 4; ++nt) {
            int gj = j0 + wx * 64 + nt * 16 + col;
            float d = acc[mt][nt][r];
            if (is_pos && gj == partner) pos_arr[gi] = d;
            v[nt] = (is_diag && gj == gi) ? -INFINITY : d;
          }
          lse_update(mrow[mt * 4 + r], srow[mt * 4 + r], v[0], v[1], v[2],
                     v[3]);
        }
    }
  }
  // reduce (m,s) across the 16 cols sharing the same rows
#pragma unroll
  for (int ri = 0; ri < 8; ++ri) {
#pragma unroll
    for (int off = 1; off < 16; off <<= 1) {
      float om = __shfl_xor(mrow[ri], off, 64);
      float os = __shfl_xor(srow[ri], off, 64);
      float mn = fmaxf(mrow[ri], om);
      float t = mn * CC;
      srow[ri] = srow[ri] * EXP2(mrow[ri] * CC - t) + os * EXP2(om * CC - t);
      mrow[ri] = mn;
    }
  }
  if (col == 0) {
    int p = chunk * 2 + wx;
#pragma unroll
    for (int ri = 0; ri < 8; ++ri) {
      int gi = bi + wy * 32 + (ri >> 2) * 16 + quad * 4 + (ri & 3);
      m_part[(size_t)p * NN + gi] = mrow[ri];
      s_part[(size_t)p * NN + gi] = srow[ri];
    }
  }
}

// ---------------- combine partials per row ----------------
__global__ __launch_bounds__(256) void k_combine(
    const float* __restrict__ m_part, const float* __restrict__ s_part,
    const float* __restrict__ pos_arr, float* __restrict__ row_loss) {
  const int i = blockIdx.x * 256 + threadIdx.x;
  float M = -INFINITY;
#pragma unroll
  for (int p = 0; p < 32; ++p) M = fmaxf(M, m_part[(size_t)p * NN + i]);
  float S = 0.f;
  float t = M * CC;
#pragma unroll
  for (int p = 0; p < 32; ++p)
    S += s_part[(size_t)p * NN + i] * EXP2(m_part[(size_t)p * NN + i] * CC - t);
  row_loss[i] = (M - pos_arr[i]) * INV_T + logf(S);
}

// ---------------- mean over rows ----------------
__global__ __launch_bounds__(256) void k_final(
    const float* __restrict__ row_loss, float* __restrict__ out) {
  const int tid = threadIdx.x;
  float s = 0.f;
#pragma unroll
  for (int l = 0; l < 32; ++l) s += row_loss[tid + l * 256];
#pragma unroll
  for (int off = 32; off > 0; off >>= 1) s += __shfl_down(s, off);
  __shared__ float red[4];
  const int wave = tid >> 6, lane = tid & 63;
  if (lane == 0) red[wave] = s;
  __syncthreads();
  if (tid == 0) out[0] = (red[0] + red[1] + red[2] + red[3]) * (1.0f / NN);
}

extern "C" void kernel_launch(void* const* d_in, const int* in_sizes, int n_in,
                              void* d_out, int out_size, void* d_ws,
                              size_t ws_size, hipStream_t stream) {
  const float* x       = (const float*)d_in[0];
  const float* dense_w = (const float*)d_in[1];
  const float* dense_b = (const float*)d_in[2];
  const float* ln_g    = (const float*)d_in[3];
  const float* ln_b    = (const float*)d_in[4];
  const float* dec_w   = (const float*)d_in[5];
  const float* dec_b   = (const float*)d_in[6];
  float* out = (float*)d_out;
  char* ws = (char*)d_ws;
  // Phase 1 layout
  uint16_t* xb = (uint16_t*)(ws);              // 16 MiB [8192][1024] bf16
  uint16_t* wt = (uint16_t*)(ws + 16777216);   //  2 MiB [1024][1024] bf16 (W^T)
  uint16_t* h  = (uint16_t*)(ws + 18874368);   // 16 MiB [8192][1024] bf16
  // Phase 2 layout (reuses xb/wt region, both dead after gemm1)
  uint16_t* wt2     = (uint16_t*)(ws);             // 256 KiB [128][1024]
  uint16_t* z       = (uint16_t*)(ws + 262144);    //   2 MiB [8192][128]
  float*    m_part  = (float*)(ws + 2359296);      //   1 MiB [32][8192]
  float*    s_part  = (float*)(ws + 3407872);      //   1 MiB
  float*    pos_arr = (float*)(ws + 4456448);      //  32 KiB
  float*    row_loss= (float*)(ws + 4489216);      //  32 KiB

  k_conv<<<dim3(NN * HID / 1024), 256, 0, stream>>>(x, xb);
  k_transpose<<<dim3(32, 32), 256, 0, stream>>>(dense_w, wt, HID, HID);
  k_gemm1<<<dim3(HID / 128, NN / 64), 256, 0, stream>>>(xb, wt, dense_b, h);
  // xb/wt dead from here; phase-2 buffers live in their region
  k_transpose<<<dim3(PROJ / 32, HID / 32), 256, 0, stream>>>(dec_w, wt2, HID,
                                                             PROJ);
  k_layernorm<<<dim3(NN), 256, 0, stream>>>(h, ln_g, ln_b);
  k_gemm2<<<dim3(NN / 32), 256, 0, stream>>>(h, wt2, dec_b, z);
  k_sim<<<dim3(NN / 64, 16), 256, 0, stream>>>(z, m_part, s_part, pos_arr);
  k_combine<<<dim3(NN / 256), 256, 0, stream>>>(m_part, s_part, pos_arr,
                                                row_loss);
  k_final<<<dim3(1), 256, 0, stream>>>(row_loss, out);
}